// Round 5
// baseline (23.451 us; speedup 1.0000x reference)
//
#include <hip/hip_runtime.h>
#include <math.h>

#define BB 64
#define KMAX 512
#define DD 256
#define CC 1000

__device__ __forceinline__ float wave_reduce_sum(float v) {
    #pragma unroll
    for (int off = 32; off > 0; off >>= 1) v += __shfl_xor(v, off, 64);
    return v;
}

// K1: one 64-lane wave per TWO adjacent (b,k) rows (same b: k0 is even, so
// row1 = row0+1 never crosses a b boundary).
//   s[b,k]  = -w[b,k] * ||deep[b] - n[b,k]||        (D = 256 -> 1 float4/lane)
//   ce[b,k] = log(sum_c exp(cls[b,k,c])) - cls[b,k,target[b]]
// No max-subtraction: cls ~ N(0,1), s in [-23,0] -> direct sum-exp safe in f32.
// Waves with k0 >= len exit before touching memory (~2x traffic cut). A dead
// row1 (odd-length boundary, <=1 wave per b) is computed but its store gated.
// Also zeroes out[0] for K2's atomicAdd (stream-ordered before K2).
__global__ void __launch_bounds__(256)
dos_row_kernel(const float* __restrict__ deep, const float* __restrict__ n,
               const float* __restrict__ w, const float* __restrict__ cls,
               const int* __restrict__ target, const int* __restrict__ lengths,
               float* __restrict__ s_out, float* __restrict__ ce_out,
               float* __restrict__ out) {
    const int wid  = threadIdx.x >> 6;
    const int lane = threadIdx.x & 63;
    const int row0 = blockIdx.x * 8 + wid * 2;      // b*KMAX + k0 (k0 even)
    const int b    = row0 >> 9;                     // KMAX = 512
    const int k0   = row0 & (KMAX - 1);

    if (blockIdx.x == 0 && threadIdx.x == 0) out[0] = 0.f;

    const int len = lengths[b];
    if (k0 >= len) return;                          // wave-uniform early exit
    const bool live1 = (k0 + 1) < len;

    // ---- issue all loads up front (~10 float4 in flight per lane) ----
    const float4 dv  = ((const float4*)(deep + (size_t)b * DD))[lane];
    const float4 nv0 = ((const float4*)(n + (size_t)row0 * DD))[lane];
    const float4 nv1 = ((const float4*)(n + (size_t)(row0 + 1) * DD))[lane];
    const float* __restrict__ x0 = cls + (size_t)row0 * CC;
    const float* __restrict__ x1 = x0 + CC;
    const float4 a0 = ((const float4*)x0)[lane];
    const float4 a1 = ((const float4*)x0)[lane + 64];
    const float4 a2 = ((const float4*)x0)[lane + 128];
    float4 a3 = make_float4(-1e30f, -1e30f, -1e30f, -1e30f);
    if (lane < 58) a3 = ((const float4*)x0)[lane + 192];   // 250 float4 = C
    const float4 c0 = ((const float4*)x1)[lane];
    const float4 c1 = ((const float4*)x1)[lane + 64];
    const float4 c2 = ((const float4*)x1)[lane + 128];
    float4 c3 = make_float4(-1e30f, -1e30f, -1e30f, -1e30f);
    if (lane < 58) c3 = ((const float4*)x1)[lane + 192];

    // ---- dist (both rows) ----
    float d0x = dv.x - nv0.x, d0y = dv.y - nv0.y, d0z = dv.z - nv0.z, d0w = dv.w - nv0.w;
    float d1x = dv.x - nv1.x, d1y = dv.y - nv1.y, d1z = dv.z - nv1.z, d1w = dv.w - nv1.w;
    float acc0 = d0x*d0x + d0y*d0y + d0z*d0z + d0w*d0w;
    float acc1 = d1x*d1x + d1y*d1y + d1z*d1z + d1w*d1w;
    acc0 = wave_reduce_sum(acc0);
    acc1 = wave_reduce_sum(acc1);

    // ---- CE denom: direct sum-exp (-1e30 fill underflows to exactly 0) ----
    float e0 = __expf(a0.x) + __expf(a0.y) + __expf(a0.z) + __expf(a0.w)
             + __expf(a1.x) + __expf(a1.y) + __expf(a1.z) + __expf(a1.w)
             + __expf(a2.x) + __expf(a2.y) + __expf(a2.z) + __expf(a2.w)
             + __expf(a3.x) + __expf(a3.y) + __expf(a3.z) + __expf(a3.w);
    float e1 = __expf(c0.x) + __expf(c0.y) + __expf(c0.z) + __expf(c0.w)
             + __expf(c1.x) + __expf(c1.y) + __expf(c1.z) + __expf(c1.w)
             + __expf(c2.x) + __expf(c2.y) + __expf(c2.z) + __expf(c2.w)
             + __expf(c3.x) + __expf(c3.y) + __expf(c3.z) + __expf(c3.w);
    e0 = wave_reduce_sum(e0);
    e1 = wave_reduce_sum(e1);

    if (lane == 0) {
        const int t = target[b];
        s_out[row0]  = -w[row0] * sqrtf(acc0);
        ce_out[row0] = __logf(e0) - x0[t];          // x[t] just streamed -> L1/L2 hot
        if (live1) {
            s_out[row0 + 1]  = -w[row0 + 1] * sqrtf(acc1);
            ce_out[row0 + 1] = __logf(e1) - x1[t];
        }
    }
}

// K2: per-b masked softmax over K fused with both reductions; 64 atomicAdds
// into out[0] (zeroed by K1). No max pass: s in [-23,0] -> exp(s) safe in f32.
// part[b] = sum_k s  +  ( sum_k exp(s)*ce ) / ( sum_k exp(s) )   over k < len
__global__ void __launch_bounds__(512)
dos_combine_kernel(const float* __restrict__ s, const float* __restrict__ ce,
                   const int* __restrict__ lengths, float* __restrict__ out) {
    const int b = blockIdx.x;
    const int k = threadIdx.x;                      // 512 threads = KMAX
    const bool valid = k < lengths[b];

    const float sv = s[b * KMAX + k];               // dead entries: garbage, gated below
    const float cv = ce[b * KMAX + k];

    float e  = valid ? __expf(sv) : 0.f;
    float fs = valid ? sv : 0.f;
    float ec = valid ? e * cv : 0.f;

    e  = wave_reduce_sum(e);
    fs = wave_reduce_sum(fs);
    ec = wave_reduce_sum(ec);

    __shared__ float r1[8], r2[8], r3[8];
    if ((k & 63) == 0) { r1[k >> 6] = e; r2[k >> 6] = fs; r3[k >> 6] = ec; }
    __syncthreads();
    if (k == 0) {
        float se = 0.f, sf = 0.f, sc = 0.f;
        #pragma unroll
        for (int i = 0; i < 8; i++) { se += r1[i]; sf += r2[i]; sc += r3[i]; }
        atomicAdd(out, sf + sc / se);
    }
}

extern "C" void kernel_launch(void* const* d_in, const int* in_sizes, int n_in,
                              void* d_out, int out_size, void* d_ws, size_t ws_size,
                              hipStream_t stream) {
    const float* deep    = (const float*)d_in[0];   // [B, D]
    const float* n       = (const float*)d_in[1];   // [B, KMAX, D]
    const float* w       = (const float*)d_in[2];   // [B, KMAX]
    const float* cls     = (const float*)d_in[3];   // [B, KMAX, C]
    const int*   target  = (const int*)d_in[4];     // [B]
    const int*   lengths = (const int*)d_in[5];     // [B]
    float*       out     = (float*)d_out;

    float* ws = (float*)d_ws;
    float* s  = ws;                                 // B*KMAX floats
    float* ce = ws + BB * KMAX;                     // B*KMAX floats

    dos_row_kernel<<<(BB * KMAX) / 8, 256, 0, stream>>>(deep, n, w, cls, target,
                                                        lengths, s, ce, out);
    dos_combine_kernel<<<BB, KMAX, 0, stream>>>(s, ce, lengths, out);
}